// Round 5
// baseline (2749.949 us; speedup 1.0000x reference)
//
#include <hip/hip_runtime.h>
#include <cstddef>

#define Pp    3
#define Cc    64
#define IMGi  48
#define Gg    16
#define Dd    576
#define NHh   12
#define HDd   48
#define HIDh  2304
#define NLl   4
#define Ss    256
#define Bb    4
#define Mm    1024          // S*B tokens
#define EPSf  1e-5f
#define NJOBS 43

typedef short short8 __attribute__((ext_vector_type(8)));
typedef short short4v __attribute__((ext_vector_type(4)));
typedef float f32x4  __attribute__((ext_vector_type(4)));

struct QJobs { const float* ptr[NJOBS]; int n[NJOBS]; int off[NJOBS]; };

// float -> bf16 (RNE), bit-level
__device__ __forceinline__ short f2bf(float f) {
  unsigned u = __float_as_uint(f);
  u = u + 0x7fffu + ((u >> 16) & 1u);
  return (short)(u >> 16);
}

// ---------------- small utility kernels ----------------

__global__ void k_zero(float* p, int n) {
  int i = blockIdx.x * blockDim.x + threadIdx.x;
  if (i < n) p[i] = 0.f;
}

// float4-vectorized abs-sum; 128 blocks per job
__global__ void k_abssum(QJobs jobs, float* absum) {
  int job = blockIdx.x >> 7, blk = blockIdx.x & 127;
  const float4* p = (const float4*)jobs.ptr[job];
  int n4 = jobs.n[job] >> 2;
  float s = 0.f;
  for (int i = blk * 256 + threadIdx.x; i < n4; i += 128 * 256) {
    float4 f = p[i];
    s += fabsf(f.x) + fabsf(f.y) + fabsf(f.z) + fabsf(f.w);
  }
  __shared__ float red[256];
  red[threadIdx.x] = s; __syncthreads();
  for (int o = 128; o > 0; o >>= 1) {
    if (threadIdx.x < o) red[threadIdx.x] += red[threadIdx.x + o];
    __syncthreads();
  }
  if (threadIdx.x == 0) atomicAdd(&absum[job], red[0]);
}

__global__ void k_alpha(QJobs jobs, const float* absum, float* alpha, float* inva) {
  int j = threadIdx.x;
  if (j < NJOBS) {
    float a = 2.f * (absum[j] / (float)jobs.n[j]) / sqrtf(7.f);
    alpha[j] = a;
    inva[j] = 1.f / a;
  }
}

// float4-vectorized quantize: wq = bf16( rint(clamp(w/alpha,-8,7)) )  (q exact in bf16)
__global__ void k_quant(QJobs jobs, const float* __restrict__ inva, short* __restrict__ wq) {
  int job = blockIdx.x >> 7, blk = blockIdx.x & 127;
  const float4* p = (const float4*)jobs.ptr[job];
  int n4 = jobs.n[job] >> 2;
  short4v* dst = (short4v*)(wq + (size_t)jobs.off[job]);
  float ia = inva[job];
  for (int i = blk * 256 + threadIdx.x; i < n4; i += 128 * 256) {
    float4 f = p[i];
    short4v q = { f2bf(rintf(fminf(7.f, fmaxf(-8.f, f.x * ia)))),
                  f2bf(rintf(fminf(7.f, fmaxf(-8.f, f.y * ia)))),
                  f2bf(rintf(fminf(7.f, fmaxf(-8.f, f.z * ia)))),
                  f2bf(rintf(fminf(7.f, fmaxf(-8.f, f.w * ia)))) };
    dst[i] = q;
  }
}

// x:(B,C,48,48) fp32 -> t:(S,B,D) fp32 ; row = s*B+b
__global__ void k_patchify(const float* __restrict__ x, float* __restrict__ t) {
  int i = blockIdx.x * 256 + threadIdx.x;
  if (i >= Mm * Dd) return;
  int d = i % Dd, row = i / Dd;
  int b = row % Bb, s = row / Bb;
  int c = d / 9, r = d % 9;
  int p1 = r / 3, p2 = r % 3;
  int g1 = s / Gg, g2 = s % Gg;
  t[i] = x[((size_t)(b * Cc + c) * IMGi + (g1 * Pp + p1)) * IMGi + (g2 * Pp + p2)];
}

// H:(S,B,D) fp32 -> out:(B,C,48,48) fp32
__global__ void k_unpatch(const float* __restrict__ h, float* __restrict__ out) {
  int i = blockIdx.x * 256 + threadIdx.x;
  if (i >= Bb * Cc * IMGi * IMGi) return;
  int j = i % IMGi, t = i / IMGi;
  int r = t % IMGi; t /= IMGi;
  int c = t % Cc;
  int b = t / Cc;
  int g1 = r / Pp, p1 = r % Pp, g2 = j / Pp, p2 = j % Pp;
  int s = g1 * Gg + g2;
  int d = c * 9 + p1 * 3 + p2;
  out[i] = h[(size_t)(s * Bb + b) * Dd + d];
}

// ---------------- layernorm (+ optional query-embed add, dual output) ----------------
// y  (if non-null): ln(x)
// yq (if non-null): ln(x) + qe[s]   where s = row>>2
__global__ void k_ln(const float* __restrict__ x, const float* __restrict__ g,
                     const float* __restrict__ b,
                     const float* __restrict__ qew, const int* __restrict__ qidx,
                     float* y, float* yq) {
  __shared__ float r1[256], r2[256];
  int row = blockIdx.x, t = threadIdx.x;
  const float* xr = x + (size_t)row * Dd;
  float s = 0.f, s2 = 0.f;
  for (int i = t; i < Dd; i += 256) { float v = xr[i]; s += v; s2 += v * v; }
  r1[t] = s; r2[t] = s2; __syncthreads();
  for (int o = 128; o > 0; o >>= 1) {
    if (t < o) { r1[t] += r1[t + o]; r2[t] += r2[t + o]; }
    __syncthreads();
  }
  float mean = r1[0] / Dd;
  float var  = r2[0] / Dd - mean * mean;
  float inv  = rsqrtf(var + EPSf);
  float* yr  = y  ? y  + (size_t)row * Dd : nullptr;
  float* yqr = yq ? yq + (size_t)row * Dd : nullptr;
  const float* qe = nullptr;
  if (yq) qe = qew + (size_t)qidx[0] * Ss * Dd + (size_t)(row >> 2) * Dd;
  for (int i = t; i < Dd; i += 256) {
    float v = (xr[i] - mean) * inv * g[i] + b[i];
    if (yr)  yr[i]  = v;
    if (yqr) yqr[i] = v + qe[i];
  }
}

// ---------------- MFMA GEMM ----------------
// out[m,n] = act( alpha * sum_k X[m,k]*q[n,k] + bias[n] + pos[m>>2,n] + res[m,n] )
// Block tile 128x128, 4 waves (2x2), wave tile 64x64 (4x4 frags of 16x16x32 bf16).
// N need not divide 128: B staging row clamped, stores guarded.
#define MT 128
#define NT 128
#define BK 32
#define LDSP 40   // padded row stride (shorts): 80B -> 2-way bank aliasing (free)

__global__ __launch_bounds__(256)
void k_gemm_mfma(const float* __restrict__ X, int ldx,
                 const float* __restrict__ Wraw,
                 const short* __restrict__ Wq,
                 const float* __restrict__ bias,
                 const float* res, int ldr,
                 const float* __restrict__ pos,
                 float* out, int ldo, float* out2,
                 int N, int K,
                 const float* __restrict__ alpha_p, const float* __restrict__ inva_p,
                 int slot, int relu)
{
  __shared__ short As[MT][LDSP];
  __shared__ short Bs[NT][LDSP];
  const int tid  = threadIdx.x;
  const int wave = tid >> 6, lane = tid & 63;
  const int quad = lane >> 4, l15 = lane & 15;
  const int tile_m = blockIdx.y * MT, tile_n = blockIdx.x * NT;
  const int m_off = (wave >> 1) * 64, n_off = (wave & 1) * 64;
  const int sr = tid >> 1;            // staging row 0..127
  const int sc = (tid & 1) * 16;      // staging k offset 0/16
  const float inva = inva_p[slot];
  const int brow = min(tile_n + sr, N - 1);

  f32x4 acc[4][4];
  #pragma unroll
  for (int i = 0; i < 4; ++i)
    #pragma unroll
    for (int jj = 0; jj < 4; ++jj) acc[i][jj] = (f32x4){0,0,0,0};

  for (int k0 = 0; k0 < K; k0 += BK) {
    // stage A: 16 fp32 -> bf16 per thread
    const float* ax = X + (size_t)(tile_m + sr) * ldx + k0 + sc;
    float4 a0 = *(const float4*)ax;
    float4 a1 = *(const float4*)(ax + 4);
    float4 a2 = *(const float4*)(ax + 8);
    float4 a3 = *(const float4*)(ax + 12);
    short8 av0, av1;
    av0[0] = f2bf(a0.x); av0[1] = f2bf(a0.y); av0[2] = f2bf(a0.z); av0[3] = f2bf(a0.w);
    av0[4] = f2bf(a1.x); av0[5] = f2bf(a1.y); av0[6] = f2bf(a1.z); av0[7] = f2bf(a1.w);
    av1[0] = f2bf(a2.x); av1[1] = f2bf(a2.y); av1[2] = f2bf(a2.z); av1[3] = f2bf(a2.w);
    av1[4] = f2bf(a3.x); av1[5] = f2bf(a3.y); av1[6] = f2bf(a3.z); av1[7] = f2bf(a3.w);
    // stage B: 16 bf16 q-values per thread
    short8 bv0, bv1;
    if (Wq) {
      const short* wp = Wq + (size_t)brow * K + k0 + sc;
      bv0 = *(const short8*)wp;
      bv1 = *(const short8*)(wp + 8);
    } else {
      const float* wx = Wraw + (size_t)brow * K + k0 + sc;
      float4 w0 = *(const float4*)wx;
      float4 w1 = *(const float4*)(wx + 4);
      float4 w2 = *(const float4*)(wx + 8);
      float4 w3 = *(const float4*)(wx + 12);
      bv0[0] = f2bf(rintf(fminf(7.f, fmaxf(-8.f, w0.x * inva))));
      bv0[1] = f2bf(rintf(fminf(7.f, fmaxf(-8.f, w0.y * inva))));
      bv0[2] = f2bf(rintf(fminf(7.f, fmaxf(-8.f, w0.z * inva))));
      bv0[3] = f2bf(rintf(fminf(7.f, fmaxf(-8.f, w0.w * inva))));
      bv0[4] = f2bf(rintf(fminf(7.f, fmaxf(-8.f, w1.x * inva))));
      bv0[5] = f2bf(rintf(fminf(7.f, fmaxf(-8.f, w1.y * inva))));
      bv0[6] = f2bf(rintf(fminf(7.f, fmaxf(-8.f, w1.z * inva))));
      bv0[7] = f2bf(rintf(fminf(7.f, fmaxf(-8.f, w1.w * inva))));
      bv1[0] = f2bf(rintf(fminf(7.f, fmaxf(-8.f, w2.x * inva))));
      bv1[1] = f2bf(rintf(fminf(7.f, fmaxf(-8.f, w2.y * inva))));
      bv1[2] = f2bf(rintf(fminf(7.f, fmaxf(-8.f, w2.z * inva))));
      bv1[3] = f2bf(rintf(fminf(7.f, fmaxf(-8.f, w2.w * inva))));
      bv1[4] = f2bf(rintf(fminf(7.f, fmaxf(-8.f, w3.x * inva))));
      bv1[5] = f2bf(rintf(fminf(7.f, fmaxf(-8.f, w3.y * inva))));
      bv1[6] = f2bf(rintf(fminf(7.f, fmaxf(-8.f, w3.z * inva))));
      bv1[7] = f2bf(rintf(fminf(7.f, fmaxf(-8.f, w3.w * inva))));
    }
    *(short8*)&As[sr][sc]     = av0;
    *(short8*)&As[sr][sc + 8] = av1;
    *(short8*)&Bs[sr][sc]     = bv0;
    *(short8*)&Bs[sr][sc + 8] = bv1;
    __syncthreads();
    short8 af[4], bf[4];
    #pragma unroll
    for (int i = 0; i < 4; ++i) af[i] = *(short8*)&As[m_off + i * 16 + l15][quad * 8];
    #pragma unroll
    for (int jj = 0; jj < 4; ++jj) bf[jj] = *(short8*)&Bs[n_off + jj * 16 + l15][quad * 8];
    #pragma unroll
    for (int i = 0; i < 4; ++i)
      #pragma unroll
      for (int jj = 0; jj < 4; ++jj)
        acc[i][jj] = __builtin_amdgcn_mfma_f32_16x16x32_bf16(af[i], bf[jj], acc[i][jj], 0, 0, 0);
    __syncthreads();
  }

  const float a_s = alpha_p[slot];
  // C/D layout (16x16x32 bf16): col = lane&15, row = quad*4 + reg   [measured m89/m91]
  #pragma unroll
  for (int i = 0; i < 4; ++i) {
    #pragma unroll
    for (int jj = 0; jj < 4; ++jj) {
      int row = tile_m + m_off + i * 16 + quad * 4;
      int col = tile_n + n_off + jj * 16 + l15;
      if (col < N) {
        float bv = bias ? bias[col] : 0.f;
        #pragma unroll
        for (int r = 0; r < 4; ++r) {
          float v = acc[i][jj][r] * a_s + bv;
          if (pos) v += pos[(size_t)((row + r) >> 2) * Dd + col];
          if (res) v += res[(size_t)(row + r) * ldr + col];
          if (relu) v = fmaxf(v, 0.f);
          out[(size_t)(row + r) * ldo + col] = v;
          if (out2) out2[(size_t)(row + r) * ldo + col] = v;
        }
      }
    }
  }
}

// ---------------- fused flash attention ----------------
// grid: (S/64 q-tiles, B*NH). 256 thr = 4 waves; wave w owns 16 query cols.
// QKV row (s*B+b), ld=1728: q[0:576), k[576:1152), v[1152:1728). out: CTX (M x 576).
__global__ __launch_bounds__(256)
void k_attn(const float* __restrict__ QKV, float* __restrict__ ctx, float scale) {
  __shared__ short Ks[256][72];
  __shared__ short Qs[64][72];
  __shared__ short Vt[48][264];
  __shared__ short Pq[64][264];
  const int qt = blockIdx.x;
  const int b  = blockIdx.y / NHh, h = blockIdx.y % NHh;
  const int tid = threadIdx.x;
  const int w = tid >> 6, lane = tid & 63, quad = lane >> 4, l15 = lane & 15;

  {
    const float* kp = QKV + (size_t)(tid * Bb + b) * 1728 + Dd + h * HDd;
    #pragma unroll
    for (int d0 = 0; d0 < 48; d0 += 4) {
      float4 f = *(const float4*)(kp + d0);
      short4v v = { f2bf(f.x), f2bf(f.y), f2bf(f.z), f2bf(f.w) };
      *(short4v*)&Ks[tid][d0] = v;
    }
    short4v z = {0, 0, 0, 0};
    *(short4v*)&Ks[tid][48] = z; *(short4v*)&Ks[tid][52] = z;
    *(short4v*)&Ks[tid][56] = z; *(short4v*)&Ks[tid][60] = z;
    const float* vp = QKV + (size_t)(tid * Bb + b) * 1728 + 2 * Dd + h * HDd;
    #pragma unroll
    for (int d0 = 0; d0 < 48; d0 += 4) {
      float4 f = *(const float4*)(vp + d0);
      Vt[d0][tid]     = f2bf(f.x);
      Vt[d0 + 1][tid] = f2bf(f.y);
      Vt[d0 + 2][tid] = f2bf(f.z);
      Vt[d0 + 3][tid] = f2bf(f.w);
    }
    if (tid < 64) {
      const float* qp = QKV + (size_t)((qt * 64 + tid) * Bb + b) * 1728 + h * HDd;
      #pragma unroll
      for (int d0 = 0; d0 < 48; d0 += 4) {
        float4 f = *(const float4*)(qp + d0);
        short4v v = { f2bf(f.x), f2bf(f.y), f2bf(f.z), f2bf(f.w) };
        *(short4v*)&Qs[tid][d0] = v;
      }
      *(short4v*)&Qs[tid][48] = z; *(short4v*)&Qs[tid][52] = z;
      *(short4v*)&Qs[tid][56] = z; *(short4v*)&Qs[tid][60] = z;
    }
  }
  __syncthreads();

  short8 bq0 = *(short8*)&Qs[w * 16 + l15][quad * 8];
  short8 bq1 = *(short8*)&Qs[w * 16 + l15][32 + quad * 8];
  f32x4 sf[16];
  #pragma unroll
  for (int mt = 0; mt < 16; ++mt) {
    f32x4 acc = {0, 0, 0, 0};
    short8 a0 = *(short8*)&Ks[mt * 16 + l15][quad * 8];
    short8 a1 = *(short8*)&Ks[mt * 16 + l15][32 + quad * 8];
    acc = __builtin_amdgcn_mfma_f32_16x16x32_bf16(a0, bq0, acc, 0, 0, 0);
    acc = __builtin_amdgcn_mfma_f32_16x16x32_bf16(a1, bq1, acc, 0, 0, 0);
    sf[mt] = acc;
  }

  float mx = -1e30f;
  #pragma unroll
  for (int mt = 0; mt < 16; ++mt)
    #pragma unroll
    for (int r = 0; r < 4; ++r) {
      sf[mt][r] *= scale;
      mx = fmaxf(mx, sf[mt][r]);
    }
  mx = fmaxf(mx, __shfl_xor(mx, 16));
  mx = fmaxf(mx, __shfl_xor(mx, 32));
  float sum = 0.f;
  #pragma unroll
  for (int mt = 0; mt < 16; ++mt)
    #pragma unroll
    for (int r = 0; r < 4; ++r) {
      float e = __expf(sf[mt][r] - mx);
      sf[mt][r] = e;
      sum += e;
    }
  sum += __shfl_xor(sum, 16);
  sum += __shfl_xor(sum, 32);
  float inv = 1.f / sum;

  #pragma unroll
  for (int mt = 0; mt < 16; ++mt) {
    short4v p = { f2bf(sf[mt][0] * inv), f2bf(sf[mt][1] * inv),
                  f2bf(sf[mt][2] * inv), f2bf(sf[mt][3] * inv) };
    *(short4v*)&Pq[w * 16 + l15][mt * 16 + quad * 4] = p;
  }
  __syncthreads();

  f32x4 of0 = {0,0,0,0}, of1 = {0,0,0,0}, of2 = {0,0,0,0};
  #pragma unroll
  for (int kt = 0; kt < 8; ++kt) {
    short8 a = *(short8*)&Pq[w * 16 + l15][kt * 32 + quad * 8];
    short8 b0 = *(short8*)&Vt[l15][kt * 32 + quad * 8];
    short8 b1 = *(short8*)&Vt[16 + l15][kt * 32 + quad * 8];
    short8 b2 = *(short8*)&Vt[32 + l15][kt * 32 + quad * 8];
    of0 = __builtin_amdgcn_mfma_f32_16x16x32_bf16(a, b0, of0, 0, 0, 0);
    of1 = __builtin_amdgcn_mfma_f32_16x16x32_bf16(a, b1, of1, 0, 0, 0);
    of2 = __builtin_amdgcn_mfma_f32_16x16x32_bf16(a, b2, of2, 0, 0, 0);
  }
  const int qg = qt * 64 + w * 16 + quad * 4;
  #pragma unroll
  for (int r = 0; r < 4; ++r) {
    float* cr = ctx + (size_t)((qg + r) * Bb + b) * Dd + h * HDd + l15;
    cr[0]  = of0[r];
    cr[16] = of1[r];
    cr[32] = of2[r];
  }
}

// ---------------- host ----------------

extern "C" void kernel_launch(void* const* d_in, const int* in_sizes, int n_in,
                              void* d_out, int out_size, void* d_ws, size_t ws_size,
                              hipStream_t stream) {
  (void)in_sizes; (void)n_in; (void)out_size;
  const float* x            = (const float*)d_in[0];
  const float* lin_enc_w    = (const float*)d_in[1];
  const float* lin_enc_b    = (const float*)d_in[2];
  const float* pos_emb      = (const float*)d_in[3];
  const float* query_embed  = (const float*)d_in[4];
  const float* enc_in_w     = (const float*)d_in[5];
  const float* enc_out_w    = (const float*)d_in[6];
  const float* enc_l1_w     = (const float*)d_in[7];
  const float* enc_l1_b     = (const float*)d_in[8];
  const float* enc_l2_w     = (const float*)d_in[9];
  const float* enc_l2_b     = (const float*)d_in[10];
  const float* enc_ln1_g    = (const float*)d_in[11];
  const float* enc_ln1_b    = (const float*)d_in[12];
  const float* enc_ln2_g    = (const float*)d_in[13];
  const float* enc_ln2_b    = (const float*)d_in[14];
  const float* dec_sa_in_w  = (const float*)d_in[15];
  const float* dec_sa_out_w = (const float*)d_in[16];
  const float* dec_ca_in_w  = (const float*)d_in[17];
  const float* dec_ca_out_w = (const float*)d_in[18];
  const float* dec_l1_w     = (const float*)d_in[19];
  const float* dec_l1_b     = (const float*)d_in[20];
  const float* dec_l2_w     = (const float*)d_in[21];
  const float* dec_l2_b     = (const float*)d_in[22];
  const float* dec_ln1_g    = (const float*)d_in[23];
  const float* dec_ln1_b    = (const float*)d_in[24];
  const float* dec_ln2_g    = (const float*)d_in[25];
  const float* dec_ln2_b    = (const float*)d_in[26];
  const float* dec_ln3_g    = (const float*)d_in[27];
  const float* dec_ln3_b    = (const float*)d_in[28];
  const float* head1_w      = (const float*)d_in[29];
  const float* head1_b      = (const float*)d_in[30];
  const float* head2_w      = (const float*)d_in[31];
  const float* head2_b      = (const float*)d_in[32];
  const int*   query_idx    = (const int*)d_in[33];
  float* out = (float*)d_out;

  const int DD  = Dd * Dd;
  const int IN3 = 3 * Dd * Dd;
  const int FF  = HIDh * Dd;
  const int MD  = Mm * Dd;

  float* ws = (float*)d_ws;
  float* ABSUM = ws;
  float* ALPHA = ws + 64;
  float* INVA  = ws + 128;
  float* H   = ws + 256;
  float* MEM = H   + MD;
  float* LN  = MEM + MD;
  float* LNQ = LN  + MD;
  float* CTX = LNQ + MD;
  float* QKV = CTX + MD;
  size_t act_floats = 256 + 5 * (size_t)MD + (size_t)Mm * HIDh;
  short* WQ = (short*)(ws + act_floats);
  const size_t WQ_ELEMS = (size_t)DD + 4 * ((size_t)IN3 + DD + FF + FF)
                        + 4 * ((size_t)IN3 + DD + IN3 + DD + FF + FF)
                        + 2 * (size_t)FF;
  const bool use_wq = ws_size >= act_floats * 4 + WQ_ELEMS * 2;

  QJobs jobs;
  int j = 0; int off = 0;
  auto addjob = [&](const float* p, int n) { jobs.ptr[j] = p; jobs.n[j] = n; jobs.off[j] = off; off += n; j++; };
  addjob(lin_enc_w, DD);
  for (int l = 0; l < NLl; ++l) addjob(enc_in_w  + (size_t)l * IN3, IN3);
  for (int l = 0; l < NLl; ++l) addjob(enc_out_w + (size_t)l * DD,  DD);
  for (int l = 0; l < NLl; ++l) addjob(enc_l1_w  + (size_t)l * FF,  FF);
  for (int l = 0; l < NLl; ++l) addjob(enc_l2_w  + (size_t)l * FF,  FF);
  for (int l = 0; l < NLl; ++l) addjob(dec_sa_in_w  + (size_t)l * IN3, IN3);
  for (int l = 0; l < NLl; ++l) addjob(dec_sa_out_w + (size_t)l * DD,  DD);
  for (int l = 0; l < NLl; ++l) addjob(dec_ca_in_w  + (size_t)l * IN3, IN3);
  for (int l = 0; l < NLl; ++l) addjob(dec_ca_out_w + (size_t)l * DD,  DD);
  for (int l = 0; l < NLl; ++l) addjob(dec_l1_w + (size_t)l * FF, FF);
  for (int l = 0; l < NLl; ++l) addjob(dec_l2_w + (size_t)l * FF, FF);
  addjob(head1_w, FF);
  addjob(head2_w, FF);

  k_zero<<<1, 64, 0, stream>>>(ABSUM, 64);
  k_abssum<<<NJOBS * 128, 256, 0, stream>>>(jobs, ABSUM);
  k_alpha<<<1, 64, 0, stream>>>(jobs, ABSUM, ALPHA, INVA);
  if (use_wq) k_quant<<<NJOBS * 128, 256, 0, stream>>>(jobs, INVA, WQ);

  auto gemm = [&](const float* X, int ldx, const float* W, int slot, long wqsub,
                  const float* bias, const float* res, int ldr, const float* pos,
                  float* o, int ldo, float* o2, int N, int K, int relu) {
    dim3 grid((N + NT - 1) / NT, Mm / MT);
    const short* wq = use_wq ? WQ + (size_t)jobs.off[slot] + wqsub : nullptr;
    const float* wr = use_wq ? nullptr : W;
    k_gemm_mfma<<<grid, 256, 0, stream>>>(X, ldx, wr, wq, bias, res, ldr, pos,
                                          o, ldo, o2, N, K, ALPHA, INVA, slot, relu);
  };

  const float scale = 1.f / sqrtf((float)HDd);
  auto attn = [&](const float* out_w, int out_slot) {
    k_attn<<<dim3(Ss / 64, Bb * NHh), 256, 0, stream>>>(QKV, CTX, scale);
    gemm(CTX, Dd, out_w, out_slot, 0, nullptr, H, Dd, nullptr, H, Dd, nullptr, Dd, Dd, 0);
  };

  const int NELEM = Mm * Dd;
  const int EB = (NELEM + 255) / 256;

  // ---- stem: patchify, then H = qlinear(t) + t + pos (pos fused in epilogue) ----
  k_patchify<<<EB, 256, 0, stream>>>(x, LN);
  gemm(LN, Dd, lin_enc_w, 0, 0, lin_enc_b, LN, Dd, pos_emb, H, Dd, nullptr, Dd, Dd, 0);

  // ---- encoder ----
  for (int l = 0; l < NLl; ++l) {
    k_ln<<<Mm, 256, 0, stream>>>(H, enc_ln1_g + l * Dd, enc_ln1_b + l * Dd, nullptr, nullptr, LN, nullptr);
    gemm(LN, Dd, enc_in_w + (size_t)l * IN3, 1 + l, 0, nullptr, nullptr, 0, nullptr, QKV, 1728, nullptr, 1728, Dd, 0);
    attn(enc_out_w + (size_t)l * DD, 5 + l);
    k_ln<<<Mm, 256, 0, stream>>>(H, enc_ln2_g + l * Dd, enc_ln2_b + l * Dd, nullptr, nullptr, LN, nullptr);
    gemm(LN, Dd, enc_l1_w + (size_t)l * FF, 9 + l, 0, enc_l1_b + l * HIDh, nullptr, 0, nullptr, QKV, HIDh, nullptr, HIDh, Dd, 1);
    // last encoder layer: dual-store H and MEM (replaces k_copy)
    gemm(QKV, HIDh, enc_l2_w + (size_t)l * FF, 13 + l, 0, enc_l2_b + l * Dd, H, Dd, nullptr,
         H, Dd, (l == NLl - 1) ? MEM : nullptr, Dd, HIDh, 0);
  }

  // ---- decoder ----
  for (int l = 0; l < NLl; ++l) {
    // self-attn: q=k from ln+qe, v from ln
    k_ln<<<Mm, 256, 0, stream>>>(H, dec_ln1_g + l * Dd, dec_ln1_b + l * Dd, query_embed, query_idx, LN, LNQ);
    gemm(LNQ, Dd, dec_sa_in_w + (size_t)l * IN3, 17 + l, 0,
         nullptr, nullptr, 0, nullptr, QKV, 1728, nullptr, 2 * Dd, Dd, 0);
    gemm(LN, Dd, dec_sa_in_w + (size_t)l * IN3 + (size_t)2 * Dd * Dd, 17 + l, (long)2 * Dd * Dd,
         nullptr, nullptr, 0, nullptr, QKV + 2 * Dd, 1728, nullptr, Dd, Dd, 0);
    attn(dec_sa_out_w + (size_t)l * DD, 21 + l);
    // cross-attn: q from ln+qe, k,v from mem
    k_ln<<<Mm, 256, 0, stream>>>(H, dec_ln2_g + l * Dd, dec_ln2_b + l * Dd, query_embed, query_idx, nullptr, LNQ);
    gemm(LNQ, Dd, dec_ca_in_w + (size_t)l * IN3, 25 + l, 0,
         nullptr, nullptr, 0, nullptr, QKV, 1728, nullptr, Dd, Dd, 0);
    gemm(MEM, Dd, dec_ca_in_w + (size_t)l * IN3 + (size_t)Dd * Dd, 25 + l, (long)Dd * Dd,
         nullptr, nullptr, 0, nullptr, QKV + Dd, 1728, nullptr, 2 * Dd, Dd, 0);
    attn(dec_ca_out_w + (size_t)l * DD, 29 + l);
    // ffn
    k_ln<<<Mm, 256, 0, stream>>>(H, dec_ln3_g + l * Dd, dec_ln3_b + l * Dd, nullptr, nullptr, LN, nullptr);
    gemm(LN, Dd, dec_l1_w + (size_t)l * FF, 33 + l, 0, dec_l1_b + l * HIDh, nullptr, 0, nullptr, QKV, HIDh, nullptr, HIDh, Dd, 1);
    gemm(QKV, HIDh, dec_l2_w + (size_t)l * FF, 37 + l, 0, dec_l2_b + l * Dd, H, Dd, nullptr, H, Dd, nullptr, Dd, HIDh, 0);
  }

  // ---- head ----
  gemm(H, Dd, head1_w, 41, 0, head1_b, nullptr, 0, nullptr, QKV, HIDh, nullptr, HIDh, Dd, 1);
  gemm(QKV, HIDh, head2_w, 42, 0, head2_b, H, Dd, nullptr, H, Dd, nullptr, Dd, HIDh, 0);

  // ---- output ----
  k_unpatch<<<EB, 256, 0, stream>>>(H, out);
}

// Round 6
// 1692.911 us; speedup vs baseline: 1.6244x; 1.6244x over previous
//
#include <hip/hip_runtime.h>
#include <cstddef>

#define Pp    3
#define Cc    64
#define IMGi  48
#define Gg    16
#define Dd    576
#define NHh   12
#define HDd   48
#define HIDh  2304
#define NLl   4
#define Ss    256
#define Bb    4
#define Mm    1024          // S*B tokens
#define EPSf  1e-5f
#define NJOBS 43

typedef short short8 __attribute__((ext_vector_type(8)));
typedef short short4v __attribute__((ext_vector_type(4)));
typedef float f32x4  __attribute__((ext_vector_type(4)));

struct QJobs { const float* ptr[NJOBS]; int n[NJOBS]; int off[NJOBS]; };

// float -> bf16 (RNE), bit-level
__device__ __forceinline__ short f2bf(float f) {
  unsigned u = __float_as_uint(f);
  u = u + 0x7fffu + ((u >> 16) & 1u);
  return (short)(u >> 16);
}

// ---------------- small utility kernels ----------------

__global__ void k_zero(float* p, int n) {
  int i = blockIdx.x * blockDim.x + threadIdx.x;
  if (i < n) p[i] = 0.f;
}

// float4-vectorized abs-sum; 128 blocks per job
__global__ void k_abssum(QJobs jobs, float* absum) {
  int job = blockIdx.x >> 7, blk = blockIdx.x & 127;
  const float4* p = (const float4*)jobs.ptr[job];
  int n4 = jobs.n[job] >> 2;
  float s = 0.f;
  for (int i = blk * 256 + threadIdx.x; i < n4; i += 128 * 256) {
    float4 f = p[i];
    s += fabsf(f.x) + fabsf(f.y) + fabsf(f.z) + fabsf(f.w);
  }
  __shared__ float red[256];
  red[threadIdx.x] = s; __syncthreads();
  for (int o = 128; o > 0; o >>= 1) {
    if (threadIdx.x < o) red[threadIdx.x] += red[threadIdx.x + o];
    __syncthreads();
  }
  if (threadIdx.x == 0) atomicAdd(&absum[job], red[0]);
}

__global__ void k_alpha(QJobs jobs, const float* absum, float* alpha, float* inva) {
  int j = threadIdx.x;
  if (j < NJOBS) {
    float a = 2.f * (absum[j] / (float)jobs.n[j]) / sqrtf(7.f);
    alpha[j] = a;
    inva[j] = 1.f / a;
  }
}

// float4-vectorized quantize: wq = bf16( rint(clamp(w/alpha,-8,7)) )  (q exact in bf16)
__global__ void k_quant(QJobs jobs, const float* __restrict__ inva, short* __restrict__ wq) {
  int job = blockIdx.x >> 7, blk = blockIdx.x & 127;
  const float4* p = (const float4*)jobs.ptr[job];
  int n4 = jobs.n[job] >> 2;
  short4v* dst = (short4v*)(wq + (size_t)jobs.off[job]);
  float ia = inva[job];
  for (int i = blk * 256 + threadIdx.x; i < n4; i += 128 * 256) {
    float4 f = p[i];
    short4v q = { f2bf(rintf(fminf(7.f, fmaxf(-8.f, f.x * ia)))),
                  f2bf(rintf(fminf(7.f, fmaxf(-8.f, f.y * ia)))),
                  f2bf(rintf(fminf(7.f, fmaxf(-8.f, f.z * ia)))),
                  f2bf(rintf(fminf(7.f, fmaxf(-8.f, f.w * ia)))) };
    dst[i] = q;
  }
}

// x:(B,C,48,48) fp32 -> t:(S,B,D) fp32 ; row = s*B+b
__global__ void k_patchify(const float* __restrict__ x, float* __restrict__ t) {
  int i = blockIdx.x * 256 + threadIdx.x;
  if (i >= Mm * Dd) return;
  int d = i % Dd, row = i / Dd;
  int b = row % Bb, s = row / Bb;
  int c = d / 9, r = d % 9;
  int p1 = r / 3, p2 = r % 3;
  int g1 = s / Gg, g2 = s % Gg;
  t[i] = x[((size_t)(b * Cc + c) * IMGi + (g1 * Pp + p1)) * IMGi + (g2 * Pp + p2)];
}

// H:(S,B,D) fp32 -> out:(B,C,48,48) fp32
__global__ void k_unpatch(const float* __restrict__ h, float* __restrict__ out) {
  int i = blockIdx.x * 256 + threadIdx.x;
  if (i >= Bb * Cc * IMGi * IMGi) return;
  int j = i % IMGi, t = i / IMGi;
  int r = t % IMGi; t /= IMGi;
  int c = t % Cc;
  int b = t / Cc;
  int g1 = r / Pp, p1 = r % Pp, g2 = j / Pp, p2 = j % Pp;
  int s = g1 * Gg + g2;
  int d = c * 9 + p1 * 3 + p2;
  out[i] = h[(size_t)(s * Bb + b) * Dd + d];
}

// ---------------- layernorm (+ optional query-embed add, dual output) ----------------
__global__ void k_ln(const float* __restrict__ x, const float* __restrict__ g,
                     const float* __restrict__ b,
                     const float* __restrict__ qew, const int* __restrict__ qidx,
                     float* y, float* yq) {
  __shared__ float r1[256], r2[256];
  int row = blockIdx.x, t = threadIdx.x;
  const float* xr = x + (size_t)row * Dd;
  float s = 0.f, s2 = 0.f;
  for (int i = t; i < Dd; i += 256) { float v = xr[i]; s += v; s2 += v * v; }
  r1[t] = s; r2[t] = s2; __syncthreads();
  for (int o = 128; o > 0; o >>= 1) {
    if (t < o) { r1[t] += r1[t + o]; r2[t] += r2[t + o]; }
    __syncthreads();
  }
  float mean = r1[0] / Dd;
  float var  = r2[0] / Dd - mean * mean;
  float inv  = rsqrtf(var + EPSf);
  float* yr  = y  ? y  + (size_t)row * Dd : nullptr;
  float* yqr = yq ? yq + (size_t)row * Dd : nullptr;
  const float* qe = nullptr;
  if (yq) qe = qew + (size_t)qidx[0] * Ss * Dd + (size_t)(row >> 2) * Dd;
  for (int i = t; i < Dd; i += 256) {
    float v = (xr[i] - mean) * inv * g[i] + b[i];
    if (yr)  yr[i]  = v;
    if (yqr) yqr[i] = v + qe[i];
  }
}

// ---------------- MFMA GEMM ----------------
// out[m,n] = act( alpha * sum_k X[m,k]*q[n,k] + bias[n] + pos[m>>2,n] + res[m,n] )
// Block tile 64x64 (4 waves, wave tile 32x32 = 2x2 frags of 16x16x32 bf16).
// Double-buffered LDS + register prefetch: ONE barrier per k-step, next tile's
// global loads in flight during current MFMAs. M,N,K all multiples of 64/32.
#define MT 64
#define NT 64
#define BK 32
#define LDSP 40   // padded row stride (shorts): 80B -> 2-way bank aliasing (free)

__global__ __launch_bounds__(256)
void k_gemm_mfma(const float* __restrict__ X, int ldx,
                 const float* __restrict__ Wraw,
                 const short* __restrict__ Wq,
                 const float* __restrict__ bias,
                 const float* res, int ldr,
                 const float* __restrict__ pos,
                 float* out, int ldo, float* out2,
                 int N, int K,
                 const float* __restrict__ alpha_p, const float* __restrict__ inva_p,
                 int slot, int relu)
{
  __shared__ short As[2][MT][LDSP];
  __shared__ short Bs[2][NT][LDSP];
  const int tid  = threadIdx.x;
  const int wave = tid >> 6, lane = tid & 63;
  const int quad = lane >> 4, l15 = lane & 15;
  const int tile_m = blockIdx.y * MT, tile_n = blockIdx.x * NT;
  const int m_off = (wave >> 1) * 32, n_off = (wave & 1) * 32;
  const int sr = tid >> 2;          // staging row 0..63
  const int sc = (tid & 3) * 8;     // staging k offset 0/8/16/24
  const float inva = inva_p[slot];

  const float* aptr = X + (size_t)(tile_m + sr) * ldx + sc;
  const short* wqp  = Wq   ? Wq   + (size_t)(tile_n + sr) * K + sc : nullptr;
  const float* wrp  = Wraw ? Wraw + (size_t)(tile_n + sr) * K + sc : nullptr;

  short8 av, bv;
  auto load_tile = [&](int k0) {
    float4 a0 = *(const float4*)(aptr + k0);
    float4 a1 = *(const float4*)(aptr + k0 + 4);
    av[0] = f2bf(a0.x); av[1] = f2bf(a0.y); av[2] = f2bf(a0.z); av[3] = f2bf(a0.w);
    av[4] = f2bf(a1.x); av[5] = f2bf(a1.y); av[6] = f2bf(a1.z); av[7] = f2bf(a1.w);
    if (wqp) {
      bv = *(const short8*)(wqp + k0);
    } else {
      float4 w0 = *(const float4*)(wrp + k0);
      float4 w1 = *(const float4*)(wrp + k0 + 4);
      bv[0] = f2bf(rintf(fminf(7.f, fmaxf(-8.f, w0.x * inva))));
      bv[1] = f2bf(rintf(fminf(7.f, fmaxf(-8.f, w0.y * inva))));
      bv[2] = f2bf(rintf(fminf(7.f, fmaxf(-8.f, w0.z * inva))));
      bv[3] = f2bf(rintf(fminf(7.f, fmaxf(-8.f, w0.w * inva))));
      bv[4] = f2bf(rintf(fminf(7.f, fmaxf(-8.f, w1.x * inva))));
      bv[5] = f2bf(rintf(fminf(7.f, fmaxf(-8.f, w1.y * inva))));
      bv[6] = f2bf(rintf(fminf(7.f, fmaxf(-8.f, w1.z * inva))));
      bv[7] = f2bf(rintf(fminf(7.f, fmaxf(-8.f, w1.w * inva))));
    }
  };

  f32x4 acc00 = {0,0,0,0}, acc01 = {0,0,0,0}, acc10 = {0,0,0,0}, acc11 = {0,0,0,0};

  load_tile(0);
  int buf = 0;
  for (int k0 = 0; k0 < K; k0 += BK) {
    *(short8*)&As[buf][sr][sc] = av;
    *(short8*)&Bs[buf][sr][sc] = bv;
    __syncthreads();
    if (k0 + BK < K) load_tile(k0 + BK);   // in flight during MFMAs below
    short8 af0 = *(short8*)&As[buf][m_off + l15][quad * 8];
    short8 af1 = *(short8*)&As[buf][m_off + 16 + l15][quad * 8];
    short8 bf0 = *(short8*)&Bs[buf][n_off + l15][quad * 8];
    short8 bf1 = *(short8*)&Bs[buf][n_off + 16 + l15][quad * 8];
    acc00 = __builtin_amdgcn_mfma_f32_16x16x32_bf16(af0, bf0, acc00, 0, 0, 0);
    acc01 = __builtin_amdgcn_mfma_f32_16x16x32_bf16(af0, bf1, acc01, 0, 0, 0);
    acc10 = __builtin_amdgcn_mfma_f32_16x16x32_bf16(af1, bf0, acc10, 0, 0, 0);
    acc11 = __builtin_amdgcn_mfma_f32_16x16x32_bf16(af1, bf1, acc11, 0, 0, 0);
    buf ^= 1;
    // no second barrier: dbuf — next iter writes buf^1, whose readers all
    // passed this iter's barrier already
  }

  const float a_s = alpha_p[slot];
  const int rowb = tile_m + m_off + quad * 4;
  const int colb = tile_n + n_off + l15;
  // C/D layout (16x16x32 bf16): col = lane&15, row = quad*4 + reg   [measured m89/m91]
  f32x4 accs[4] = {acc00, acc01, acc10, acc11};
  #pragma unroll
  for (int t = 0; t < 4; ++t) {
    int row = rowb + ((t >> 1) * 16);
    int col = colb + ((t & 1) * 16);
    float bvv = bias ? bias[col] : 0.f;
    #pragma unroll
    for (int r = 0; r < 4; ++r) {
      float v = accs[t][r] * a_s + bvv;
      if (pos) v += pos[(size_t)((row + r) >> 2) * Dd + col];
      if (res) v += res[(size_t)(row + r) * ldr + col];
      if (relu) v = fmaxf(v, 0.f);
      out[(size_t)(row + r) * ldo + col] = v;
      if (out2) out2[(size_t)(row + r) * ldo + col] = v;
    }
  }
}

// ---------------- fused flash attention ----------------
// grid: (S/64 q-tiles, B*NH). 256 thr = 4 waves; wave w owns 16 query cols.
// QKV row (s*B+b), ld=1728: q[0:576), k[576:1152), v[1152:1728). out: CTX (M x 576).
__global__ __launch_bounds__(256)
void k_attn(const float* __restrict__ QKV, float* __restrict__ ctx, float scale) {
  __shared__ short Ks[256][72];
  __shared__ short Qs[64][72];
  __shared__ short Vt[48][264];
  __shared__ short Pq[64][264];
  const int qt = blockIdx.x;
  const int b  = blockIdx.y / NHh, h = blockIdx.y % NHh;
  const int tid = threadIdx.x;
  const int w = tid >> 6, lane = tid & 63, quad = lane >> 4, l15 = lane & 15;

  {
    const float* kp = QKV + (size_t)(tid * Bb + b) * 1728 + Dd + h * HDd;
    #pragma unroll
    for (int d0 = 0; d0 < 48; d0 += 4) {
      float4 f = *(const float4*)(kp + d0);
      short4v v = { f2bf(f.x), f2bf(f.y), f2bf(f.z), f2bf(f.w) };
      *(short4v*)&Ks[tid][d0] = v;
    }
    short4v z = {0, 0, 0, 0};
    *(short4v*)&Ks[tid][48] = z; *(short4v*)&Ks[tid][52] = z;
    *(short4v*)&Ks[tid][56] = z; *(short4v*)&Ks[tid][60] = z;
    const float* vp = QKV + (size_t)(tid * Bb + b) * 1728 + 2 * Dd + h * HDd;
    #pragma unroll
    for (int d0 = 0; d0 < 48; d0 += 4) {
      float4 f = *(const float4*)(vp + d0);
      Vt[d0][tid]     = f2bf(f.x);
      Vt[d0 + 1][tid] = f2bf(f.y);
      Vt[d0 + 2][tid] = f2bf(f.z);
      Vt[d0 + 3][tid] = f2bf(f.w);
    }
    if (tid < 64) {
      const float* qp = QKV + (size_t)((qt * 64 + tid) * Bb + b) * 1728 + h * HDd;
      #pragma unroll
      for (int d0 = 0; d0 < 48; d0 += 4) {
        float4 f = *(const float4*)(qp + d0);
        short4v v = { f2bf(f.x), f2bf(f.y), f2bf(f.z), f2bf(f.w) };
        *(short4v*)&Qs[tid][d0] = v;
      }
      *(short4v*)&Qs[tid][48] = z; *(short4v*)&Qs[tid][52] = z;
      *(short4v*)&Qs[tid][56] = z; *(short4v*)&Qs[tid][60] = z;
    }
  }
  __syncthreads();

  short8 bq0 = *(short8*)&Qs[w * 16 + l15][quad * 8];
  short8 bq1 = *(short8*)&Qs[w * 16 + l15][32 + quad * 8];
  f32x4 sf[16];
  #pragma unroll
  for (int mt = 0; mt < 16; ++mt) {
    f32x4 acc = {0, 0, 0, 0};
    short8 a0 = *(short8*)&Ks[mt * 16 + l15][quad * 8];
    short8 a1 = *(short8*)&Ks[mt * 16 + l15][32 + quad * 8];
    acc = __builtin_amdgcn_mfma_f32_16x16x32_bf16(a0, bq0, acc, 0, 0, 0);
    acc = __builtin_amdgcn_mfma_f32_16x16x32_bf16(a1, bq1, acc, 0, 0, 0);
    sf[mt] = acc;
  }

  float mx = -1e30f;
  #pragma unroll
  for (int mt = 0; mt < 16; ++mt)
    #pragma unroll
    for (int r = 0; r < 4; ++r) {
      sf[mt][r] *= scale;
      mx = fmaxf(mx, sf[mt][r]);
    }
  mx = fmaxf(mx, __shfl_xor(mx, 16));
  mx = fmaxf(mx, __shfl_xor(mx, 32));
  float sum = 0.f;
  #pragma unroll
  for (int mt = 0; mt < 16; ++mt)
    #pragma unroll
    for (int r = 0; r < 4; ++r) {
      float e = __expf(sf[mt][r] - mx);
      sf[mt][r] = e;
      sum += e;
    }
  sum += __shfl_xor(sum, 16);
  sum += __shfl_xor(sum, 32);
  float inv = 1.f / sum;

  #pragma unroll
  for (int mt = 0; mt < 16; ++mt) {
    short4v p = { f2bf(sf[mt][0] * inv), f2bf(sf[mt][1] * inv),
                  f2bf(sf[mt][2] * inv), f2bf(sf[mt][3] * inv) };
    *(short4v*)&Pq[w * 16 + l15][mt * 16 + quad * 4] = p;
  }
  __syncthreads();

  f32x4 of0 = {0,0,0,0}, of1 = {0,0,0,0}, of2 = {0,0,0,0};
  #pragma unroll
  for (int kt = 0; kt < 8; ++kt) {
    short8 a = *(short8*)&Pq[w * 16 + l15][kt * 32 + quad * 8];
    short8 b0 = *(short8*)&Vt[l15][kt * 32 + quad * 8];
    short8 b1 = *(short8*)&Vt[16 + l15][kt * 32 + quad * 8];
    short8 b2 = *(short8*)&Vt[32 + l15][kt * 32 + quad * 8];
    of0 = __builtin_amdgcn_mfma_f32_16x16x32_bf16(a, b0, of0, 0, 0, 0);
    of1 = __builtin_amdgcn_mfma_f32_16x16x32_bf16(a, b1, of1, 0, 0, 0);
    of2 = __builtin_amdgcn_mfma_f32_16x16x32_bf16(a, b2, of2, 0, 0, 0);
  }
  const int qg = qt * 64 + w * 16 + quad * 4;
  #pragma unroll
  for (int r = 0; r < 4; ++r) {
    float* cr = ctx + (size_t)((qg + r) * Bb + b) * Dd + h * HDd + l15;
    cr[0]  = of0[r];
    cr[16] = of1[r];
    cr[32] = of2[r];
  }
}

// ---------------- host ----------------

extern "C" void kernel_launch(void* const* d_in, const int* in_sizes, int n_in,
                              void* d_out, int out_size, void* d_ws, size_t ws_size,
                              hipStream_t stream) {
  (void)in_sizes; (void)n_in; (void)out_size;
  const float* x            = (const float*)d_in[0];
  const float* lin_enc_w    = (const float*)d_in[1];
  const float* lin_enc_b    = (const float*)d_in[2];
  const float* pos_emb      = (const float*)d_in[3];
  const float* query_embed  = (const float*)d_in[4];
  const float* enc_in_w     = (const float*)d_in[5];
  const float* enc_out_w    = (const float*)d_in[6];
  const float* enc_l1_w     = (const float*)d_in[7];
  const float* enc_l1_b     = (const float*)d_in[8];
  const float* enc_l2_w     = (const float*)d_in[9];
  const float* enc_l2_b     = (const float*)d_in[10];
  const float* enc_ln1_g    = (const float*)d_in[11];
  const float* enc_ln1_b    = (const float*)d_in[12];
  const float* enc_ln2_g    = (const float*)d_in[13];
  const float* enc_ln2_b    = (const float*)d_in[14];
  const float* dec_sa_in_w  = (const float*)d_in[15];
  const float* dec_sa_out_w = (const float*)d_in[16];
  const float* dec_ca_in_w  = (const float*)d_in[17];
  const float* dec_ca_out_w = (const float*)d_in[18];
  const float* dec_l1_w     = (const float*)d_in[19];
  const float* dec_l1_b     = (const float*)d_in[20];
  const float* dec_l2_w     = (const float*)d_in[21];
  const float* dec_l2_b     = (const float*)d_in[22];
  const float* dec_ln1_g    = (const float*)d_in[23];
  const float* dec_ln1_b    = (const float*)d_in[24];
  const float* dec_ln2_g    = (const float*)d_in[25];
  const float* dec_ln2_b    = (const float*)d_in[26];
  const float* dec_ln3_g    = (const float*)d_in[27];
  const float* dec_ln3_b    = (const float*)d_in[28];
  const float* head1_w      = (const float*)d_in[29];
  const float* head1_b      = (const float*)d_in[30];
  const float* head2_w      = (const float*)d_in[31];
  const float* head2_b      = (const float*)d_in[32];
  const int*   query_idx    = (const int*)d_in[33];
  float* out = (float*)d_out;

  const int DD  = Dd * Dd;
  const int IN3 = 3 * Dd * Dd;
  const int FF  = HIDh * Dd;
  const int MD  = Mm * Dd;

  float* ws = (float*)d_ws;
  float* ABSUM = ws;
  float* ALPHA = ws + 64;
  float* INVA  = ws + 128;
  float* H   = ws + 256;
  float* MEM = H   + MD;
  float* LN  = MEM + MD;
  float* LNQ = LN  + MD;
  float* CTX = LNQ + MD;
  float* QKV = CTX + MD;
  size_t act_floats = 256 + 5 * (size_t)MD + (size_t)Mm * HIDh;
  short* WQ = (short*)(ws + act_floats);
  const size_t WQ_ELEMS = (size_t)DD + 4 * ((size_t)IN3 + DD + FF + FF)
                        + 4 * ((size_t)IN3 + DD + IN3 + DD + FF + FF)
                        + 2 * (size_t)FF;
  const bool use_wq = ws_size >= act_floats * 4 + WQ_ELEMS * 2;

  QJobs jobs;
  int j = 0; int off = 0;
  auto addjob = [&](const float* p, int n) { jobs.ptr[j] = p; jobs.n[j] = n; jobs.off[j] = off; off += n; j++; };
  addjob(lin_enc_w, DD);
  for (int l = 0; l < NLl; ++l) addjob(enc_in_w  + (size_t)l * IN3, IN3);
  for (int l = 0; l < NLl; ++l) addjob(enc_out_w + (size_t)l * DD,  DD);
  for (int l = 0; l < NLl; ++l) addjob(enc_l1_w  + (size_t)l * FF,  FF);
  for (int l = 0; l < NLl; ++l) addjob(enc_l2_w  + (size_t)l * FF,  FF);
  for (int l = 0; l < NLl; ++l) addjob(dec_sa_in_w  + (size_t)l * IN3, IN3);
  for (int l = 0; l < NLl; ++l) addjob(dec_sa_out_w + (size_t)l * DD,  DD);
  for (int l = 0; l < NLl; ++l) addjob(dec_ca_in_w  + (size_t)l * IN3, IN3);
  for (int l = 0; l < NLl; ++l) addjob(dec_ca_out_w + (size_t)l * DD,  DD);
  for (int l = 0; l < NLl; ++l) addjob(dec_l1_w + (size_t)l * FF, FF);
  for (int l = 0; l < NLl; ++l) addjob(dec_l2_w + (size_t)l * FF, FF);
  addjob(head1_w, FF);
  addjob(head2_w, FF);

  k_zero<<<1, 64, 0, stream>>>(ABSUM, 64);
  k_abssum<<<NJOBS * 128, 256, 0, stream>>>(jobs, ABSUM);
  k_alpha<<<1, 64, 0, stream>>>(jobs, ABSUM, ALPHA, INVA);
  if (use_wq) k_quant<<<NJOBS * 128, 256, 0, stream>>>(jobs, INVA, WQ);

  auto gemm = [&](const float* X, int ldx, const float* W, int slot, long wqsub,
                  const float* bias, const float* res, int ldr, const float* pos,
                  float* o, int ldo, float* o2, int N, int K, int relu) {
    dim3 grid(N / NT, Mm / MT);
    const short* wq = use_wq ? WQ + (size_t)jobs.off[slot] + wqsub : nullptr;
    const float* wr = use_wq ? nullptr : W;
    k_gemm_mfma<<<grid, 256, 0, stream>>>(X, ldx, wr, wq, bias, res, ldr, pos,
                                          o, ldo, o2, N, K, ALPHA, INVA, slot, relu);
  };

  const float scale = 1.f / sqrtf((float)HDd);
  auto attn = [&](const float* out_w, int out_slot) {
    k_attn<<<dim3(Ss / 64, Bb * NHh), 256, 0, stream>>>(QKV, CTX, scale);
    gemm(CTX, Dd, out_w, out_slot, 0, nullptr, H, Dd, nullptr, H, Dd, nullptr, Dd, Dd, 0);
  };

  const int NELEM = Mm * Dd;
  const int EB = (NELEM + 255) / 256;

  // ---- stem: patchify, then H = qlinear(t) + t + pos (pos fused in epilogue) ----
  k_patchify<<<EB, 256, 0, stream>>>(x, LN);
  gemm(LN, Dd, lin_enc_w, 0, 0, lin_enc_b, LN, Dd, pos_emb, H, Dd, nullptr, Dd, Dd, 0);

  // ---- encoder ----
  for (int l = 0; l < NLl; ++l) {
    k_ln<<<Mm, 256, 0, stream>>>(H, enc_ln1_g + l * Dd, enc_ln1_b + l * Dd, nullptr, nullptr, LN, nullptr);
    gemm(LN, Dd, enc_in_w + (size_t)l * IN3, 1 + l, 0, nullptr, nullptr, 0, nullptr, QKV, 1728, nullptr, 1728, Dd, 0);
    attn(enc_out_w + (size_t)l * DD, 5 + l);
    k_ln<<<Mm, 256, 0, stream>>>(H, enc_ln2_g + l * Dd, enc_ln2_b + l * Dd, nullptr, nullptr, LN, nullptr);
    gemm(LN, Dd, enc_l1_w + (size_t)l * FF, 9 + l, 0, enc_l1_b + l * HIDh, nullptr, 0, nullptr, QKV, HIDh, nullptr, HIDh, Dd, 1);
    // last encoder layer: dual-store H and MEM (replaces k_copy)
    gemm(QKV, HIDh, enc_l2_w + (size_t)l * FF, 13 + l, 0, enc_l2_b + l * Dd, H, Dd, nullptr,
         H, Dd, (l == NLl - 1) ? MEM : nullptr, Dd, HIDh, 0);
  }

  // ---- decoder ----
  for (int l = 0; l < NLl; ++l) {
    // self-attn: q=k from ln+qe, v from ln
    k_ln<<<Mm, 256, 0, stream>>>(H, dec_ln1_g + l * Dd, dec_ln1_b + l * Dd, query_embed, query_idx, LN, LNQ);
    gemm(LNQ, Dd, dec_sa_in_w + (size_t)l * IN3, 17 + l, 0,
         nullptr, nullptr, 0, nullptr, QKV, 1728, nullptr, 2 * Dd, Dd, 0);
    gemm(LN, Dd, dec_sa_in_w + (size_t)l * IN3 + (size_t)2 * Dd * Dd, 17 + l, (long)2 * Dd * Dd,
         nullptr, nullptr, 0, nullptr, QKV + 2 * Dd, 1728, nullptr, Dd, Dd, 0);
    attn(dec_sa_out_w + (size_t)l * DD, 21 + l);
    // cross-attn: q from ln+qe, k,v from mem
    k_ln<<<Mm, 256, 0, stream>>>(H, dec_ln2_g + l * Dd, dec_ln2_b + l * Dd, query_embed, query_idx, nullptr, LNQ);
    gemm(LNQ, Dd, dec_ca_in_w + (size_t)l * IN3, 25 + l, 0,
         nullptr, nullptr, 0, nullptr, QKV, 1728, nullptr, Dd, Dd, 0);
    gemm(MEM, Dd, dec_ca_in_w + (size_t)l * IN3 + (size_t)Dd * Dd, 25 + l, (long)Dd * Dd,
         nullptr, nullptr, 0, nullptr, QKV + Dd, 1728, nullptr, 2 * Dd, Dd, 0);
    attn(dec_ca_out_w + (size_t)l * DD, 29 + l);
    // ffn
    k_ln<<<Mm, 256, 0, stream>>>(H, dec_ln3_g + l * Dd, dec_ln3_b + l * Dd, nullptr, nullptr, LN, nullptr);
    gemm(LN, Dd, dec_l1_w + (size_t)l * FF, 33 + l, 0, dec_l1_b + l * HIDh, nullptr, 0, nullptr, QKV, HIDh, nullptr, HIDh, Dd, 1);
    gemm(QKV, HIDh, dec_l2_w + (size_t)l * FF, 37 + l, 0, dec_l2_b + l * Dd, H, Dd, nullptr, H, Dd, nullptr, Dd, HIDh, 0);
  }

  // ---- head ----
  gemm(H, Dd, head1_w, 41, 0, head1_b, nullptr, 0, nullptr, QKV, HIDh, nullptr, HIDh, Dd, 1);
  gemm(QKV, HIDh, head2_w, 42, 0, head2_b, H, Dd, nullptr, H, Dd, nullptr, Dd, HIDh, 0);

  // ---- output ----
  k_unpatch<<<EB, 256, 0, stream>>>(H, out);
}